// Round 2
// baseline (1174.954 us; speedup 1.0000x reference)
//
#include <hip/hip_runtime.h>
#include <hip/hip_bf16.h>

// RVQ fused kernel: B=16, D=512, T=2048, NQ=9, CS=1024, CD=8.
// One WG (256 thr) owns a (D=512 x TT=32) residual tile in registers:
//   tid -> dg = tid>>5 (d-group, 64 rows each), tl = tid&31 (t within tile).
// Loop q=0..8 entirely on-chip; only outputs + per-q constants touch global.
// ws layout (floats): w_inT[9][512][8] | w_outT[9][512][8] | cnorm[9][1024][8] | csq[9][1024]

#define WS_WIN   0
#define WS_WOUT  36864
#define WS_CN    73728
#define WS_CSQ   147456

// d_out element offsets (fp32), reference return order:
// codes (16,9,2048) | z_O (16,512,2048) | z_i_s (16,9,8,2048) | z_q_s (16,9,8,2048) | z_o_s (16,9,512,2048)
#define O_ZO 294912
#define O_ZI 17072128
#define O_ZQ 19431424
#define O_ZOS 21790720

__global__ __launch_bounds__(256)
void rvq_prep(const float* __restrict__ in_v, const float* __restrict__ in_g,
              const float* __restrict__ out_v, const float* __restrict__ out_g,
              const float* __restrict__ cbs, float* __restrict__ ws) {
  const int q = blockIdx.x;
  const int tid = threadIdx.x;
  __shared__ float red[8][32];
  __shared__ float nrmc[8];

  // ---- in-proj weight-norm: norm over D=512 per output channel c ----
  {
    const int c = tid >> 5, s = tid & 31;
    const float* row = in_v + (q * 8 + c) * 512;
    float ps = 0.f;
    #pragma unroll
    for (int i = 0; i < 16; ++i) { float v = row[s * 16 + i]; ps = fmaf(v, v, ps); }
    red[c][s] = ps;
  }
  __syncthreads();
  if (tid < 8) {
    float s = 0.f;
    #pragma unroll
    for (int i = 0; i < 32; ++i) s += red[tid][i];
    nrmc[tid] = sqrtf(s);
  }
  __syncthreads();
  {
    float* dst = ws + WS_WIN + q * 4096;   // [d][c]
    const float* ivq = in_v + q * 8 * 512;
    const float* igq = in_g + q * 8;
    #pragma unroll
    for (int i = 0; i < 16; ++i) {
      int e = i * 256 + tid;
      int d = e >> 3, c = e & 7;
      dst[e] = (igq[c] * ivq[c * 512 + d]) / nrmc[c];   // (g*v)/norm, per reference
    }
  }
  // ---- out-proj weight-norm: norm over CD=8 per row d ----
  {
    float* dst = ws + WS_WOUT + q * 4096;  // [d][c]
    #pragma unroll
    for (int rr = 0; rr < 2; ++rr) {
      int d = rr * 256 + tid;
      const float* row = out_v + (size_t)(q * 512 + d) * 8;
      float4 a = *reinterpret_cast<const float4*>(row);
      float4 b = *reinterpret_cast<const float4*>(row + 4);
      float s = 0.f;
      s = fmaf(a.x, a.x, s); s = fmaf(a.y, a.y, s); s = fmaf(a.z, a.z, s); s = fmaf(a.w, a.w, s);
      s = fmaf(b.x, b.x, s); s = fmaf(b.y, b.y, s); s = fmaf(b.z, b.z, s); s = fmaf(b.w, b.w, s);
      float n = sqrtf(s);
      float g = out_g[q * 512 + d];
      dst[d * 8 + 0] = (g * a.x) / n; dst[d * 8 + 1] = (g * a.y) / n;
      dst[d * 8 + 2] = (g * a.z) / n; dst[d * 8 + 3] = (g * a.w) / n;
      dst[d * 8 + 4] = (g * b.x) / n; dst[d * 8 + 5] = (g * b.y) / n;
      dst[d * 8 + 6] = (g * b.z) / n; dst[d * 8 + 7] = (g * b.w) / n;
    }
  }
  // ---- codebook L2-normalize + squared norms ----
  {
    float* dc = ws + WS_CN + q * 8192;     // [j][c]
    float* dq = ws + WS_CSQ + q * 1024;
    #pragma unroll
    for (int rr = 0; rr < 4; ++rr) {
      int j = rr * 256 + tid;
      const float* row = cbs + (size_t)(q * 1024 + j) * 8;
      float4 a = *reinterpret_cast<const float4*>(row);
      float4 b = *reinterpret_cast<const float4*>(row + 4);
      float s = 0.f;
      s = fmaf(a.x, a.x, s); s = fmaf(a.y, a.y, s); s = fmaf(a.z, a.z, s); s = fmaf(a.w, a.w, s);
      s = fmaf(b.x, b.x, s); s = fmaf(b.y, b.y, s); s = fmaf(b.z, b.z, s); s = fmaf(b.w, b.w, s);
      float den = fmaxf(sqrtf(s), 1e-12f);
      float c0 = a.x / den, c1 = a.y / den, c2 = a.z / den, c3 = a.w / den;
      float c4 = b.x / den, c5 = b.y / den, c6 = b.z / den, c7 = b.w / den;
      float sq = 0.f;
      sq = fmaf(c0, c0, sq); sq = fmaf(c1, c1, sq); sq = fmaf(c2, c2, sq); sq = fmaf(c3, c3, sq);
      sq = fmaf(c4, c4, sq); sq = fmaf(c5, c5, sq); sq = fmaf(c6, c6, sq); sq = fmaf(c7, c7, sq);
      dc[j * 8 + 0] = c0; dc[j * 8 + 1] = c1; dc[j * 8 + 2] = c2; dc[j * 8 + 3] = c3;
      dc[j * 8 + 4] = c4; dc[j * 8 + 5] = c5; dc[j * 8 + 6] = c6; dc[j * 8 + 7] = c7;
      dq[j] = sq;
    }
  }
}

__global__ __launch_bounds__(256, 2)
void rvq_main(const float* __restrict__ z, const float* __restrict__ in_b,
              const float* __restrict__ out_b, const float* __restrict__ cbs,
              const float* __restrict__ ws, float* __restrict__ out) {
  // regA reused per phase: [0..4095] w_inT | [4096..6143] partials   (phase B)
  //                        [0..8191] cnorm | [8192..9215] csq        (phase C)
  //                        [0..4095] w_outT                          (phase D)
  __shared__ __align__(16) float regA[9216];
  __shared__ __align__(16) float ldsOb[512];
  __shared__ __align__(16) float ldsZi[32][8];
  __shared__ __align__(16) float ldsZq[32][8];
  __shared__ __align__(16) float ldsBd[32][8];
  __shared__ __align__(16) int   ldsBi[32][8];
  __shared__ float ldsIb[8];

  const int tid = threadIdx.x;
  const int dg = tid >> 5, tl = tid & 31;
  const int b = blockIdx.y;
  const int t0 = blockIdx.x * 32;
  const int t = t0 + tl;

  const float* zb = z + (size_t)b * 512 * 2048;
  float r[64];
  #pragma unroll
  for (int k = 0; k < 64; ++k)
    r[k] = zb[(size_t)(dg * 64 + k) * 2048 + t];

  float* outCodes = out;
  float* outZO = out + O_ZO;
  float* outZi = out + O_ZI;
  float* outZq = out + O_ZQ;
  float* outZo = out + O_ZOS;

  for (int q = 0; q < 9; ++q) {
    __syncthreads();                                   // (a) prev phase D done with regA
    // ---- fill1: w_inT + in bias ----
    {
      const float4* src = reinterpret_cast<const float4*>(ws + WS_WIN + q * 4096);
      float4* dst = reinterpret_cast<float4*>(regA);
      #pragma unroll
      for (int i = 0; i < 4; ++i) dst[i * 256 + tid] = src[i * 256 + tid];
      if (tid < 8) ldsIb[tid] = in_b[q * 8 + tid];
    }
    __syncthreads();                                   // (b)
    // ---- phase B: z_i partial sums over this thread's 64 d's ----
    {
      float p0=0.f,p1=0.f,p2=0.f,p3=0.f,p4=0.f,p5=0.f,p6=0.f,p7=0.f;
      #pragma unroll 16
      for (int k = 0; k < 64; ++k) {
        int d = dg * 64 + k;
        float4 wa = *reinterpret_cast<const float4*>(&regA[d * 8]);
        float4 wb = *reinterpret_cast<const float4*>(&regA[d * 8 + 4]);
        float rv = r[k];
        p0 = fmaf(wa.x, rv, p0); p1 = fmaf(wa.y, rv, p1);
        p2 = fmaf(wa.z, rv, p2); p3 = fmaf(wa.w, rv, p3);
        p4 = fmaf(wb.x, rv, p4); p5 = fmaf(wb.y, rv, p5);
        p6 = fmaf(wb.z, rv, p6); p7 = fmaf(wb.w, rv, p7);
      }
      float* part = regA + 4096 + (dg * 32 + tl) * 8;
      *reinterpret_cast<float4*>(part)     = make_float4(p0, p1, p2, p3);
      *reinterpret_cast<float4*>(part + 4) = make_float4(p4, p5, p6, p7);
    }
    __syncthreads();                                   // (c)
    // ---- reduce partials -> z_i ; store z_i_s ----
    {
      int tl2 = tid >> 3, c2 = tid & 7;
      float s = 0.f;
      #pragma unroll
      for (int g2 = 0; g2 < 8; ++g2) s += regA[4096 + (g2 * 32 + tl2) * 8 + c2];
      s += ldsIb[c2];
      ldsZi[tl2][c2] = s;
      outZi[(size_t)((b * 9 + q) * 8 + c2) * 2048 + t0 + tl2] = s;
    }
    __syncthreads();                                   // (d) partials consumed
    // ---- fill2: cnorm + csq ----
    {
      const float4* src = reinterpret_cast<const float4*>(ws + WS_CN + q * 8192);
      float4* dst = reinterpret_cast<float4*>(regA);
      #pragma unroll
      for (int i = 0; i < 8; ++i) dst[i * 256 + tid] = src[i * 256 + tid];
      const float4* srcq = reinterpret_cast<const float4*>(ws + WS_CSQ + q * 1024);
      reinterpret_cast<float4*>(regA + 8192)[tid] = srcq[tid];
    }
    __syncthreads();                                   // (e)
    // ---- phase C: NN search; thread (tl3, jc) scans j = jj*8 + jc ----
    {
      int tl3 = tid >> 3, jc = tid & 7;
      float4 va = *reinterpret_cast<const float4*>(&ldsZi[tl3][0]);
      float4 vb = *reinterpret_cast<const float4*>(&ldsZi[tl3][4]);
      float nsq = 0.f;
      nsq = fmaf(va.x, va.x, nsq); nsq = fmaf(va.y, va.y, nsq);
      nsq = fmaf(va.z, va.z, nsq); nsq = fmaf(va.w, va.w, nsq);
      nsq = fmaf(vb.x, vb.x, nsq); nsq = fmaf(vb.y, vb.y, nsq);
      nsq = fmaf(vb.z, vb.z, nsq); nsq = fmaf(vb.w, vb.w, nsq);
      float den = fmaxf(sqrtf(nsq), 1e-12f);
      float e0 = va.x / den, e1 = va.y / den, e2 = va.z / den, e3 = va.w / den;
      float e4 = vb.x / den, e5 = vb.y / den, e6 = vb.z / den, e7 = vb.w / den;
      float S = 0.f;
      S = fmaf(e0, e0, S); S = fmaf(e1, e1, S); S = fmaf(e2, e2, S); S = fmaf(e3, e3, S);
      S = fmaf(e4, e4, S); S = fmaf(e5, e5, S); S = fmaf(e6, e6, S); S = fmaf(e7, e7, S);
      float best = 3.4e38f; int bi = 0;
      #pragma unroll 8
      for (int jj = 0; jj < 128; ++jj) {
        int j = (jj << 3) | jc;
        float4 ca = *reinterpret_cast<const float4*>(&regA[j << 3]);
        float4 cb4 = *reinterpret_cast<const float4*>(&regA[(j << 3) + 4]);
        float dot = 0.f;
        dot = fmaf(e0, ca.x, dot); dot = fmaf(e1, ca.y, dot);
        dot = fmaf(e2, ca.z, dot); dot = fmaf(e3, ca.w, dot);
        dot = fmaf(e4, cb4.x, dot); dot = fmaf(e5, cb4.y, dot);
        dot = fmaf(e6, cb4.z, dot); dot = fmaf(e7, cb4.w, dot);
        float dist = (S - 2.0f * dot) + regA[8192 + j];
        if (dist < best) { best = dist; bi = j; }      // strict < => first (lowest) idx
      }
      ldsBd[tl3][jc] = best; ldsBi[tl3][jc] = bi;
    }
    __syncthreads();                                   // (f)
    // ---- reduce argmin; codes + z_q ----
    if (tid < 32) {
      float bd = ldsBd[tid][0]; int bi = ldsBi[tid][0];
      #pragma unroll
      for (int jc = 1; jc < 8; ++jc) {
        float d2 = ldsBd[tid][jc]; int i2 = ldsBi[tid][jc];
        if (d2 < bd || (d2 == bd && i2 < bi)) { bd = d2; bi = i2; }
      }
      outCodes[(size_t)(b * 9 + q) * 2048 + t0 + tid] = (float)bi;
      const float* row = cbs + (size_t)(q * 1024 + bi) * 8;  // RAW codebook row
      #pragma unroll
      for (int c = 0; c < 8; ++c) {
        float ziv = ldsZi[tid][c];
        float zq = ziv + (row[c] - ziv);               // STE exactly as reference
        ldsZq[tid][c] = zq;
        outZq[(size_t)((b * 9 + q) * 8 + c) * 2048 + t0 + tid] = zq;
      }
    }
    __syncthreads();                                   // (g)
    // ---- fill3: w_outT + out bias ----
    {
      const float4* src = reinterpret_cast<const float4*>(ws + WS_WOUT + q * 4096);
      float4* dst = reinterpret_cast<float4*>(regA);
      #pragma unroll
      for (int i = 0; i < 4; ++i) dst[i * 256 + tid] = src[i * 256 + tid];
      ldsOb[tid] = out_b[q * 512 + tid];
      ldsOb[256 + tid] = out_b[q * 512 + 256 + tid];
    }
    __syncthreads();                                   // (h)
    // ---- phase D: z_o = w_out @ z_q + ob ; store; r -= z_o ----
    {
      float4 qa = *reinterpret_cast<const float4*>(&ldsZq[tl][0]);
      float4 qb = *reinterpret_cast<const float4*>(&ldsZq[tl][4]);
      float* outZoQ = outZo + (size_t)((b * 9 + q) * 512) * 2048 + t;
      #pragma unroll 16
      for (int k = 0; k < 64; ++k) {
        int d = dg * 64 + k;
        float4 wa = *reinterpret_cast<const float4*>(&regA[d * 8]);
        float4 wb = *reinterpret_cast<const float4*>(&regA[d * 8 + 4]);
        float dot = 0.f;
        dot = fmaf(wa.x, qa.x, dot); dot = fmaf(wa.y, qa.y, dot);
        dot = fmaf(wa.z, qa.z, dot); dot = fmaf(wa.w, qa.w, dot);
        dot = fmaf(wb.x, qb.x, dot); dot = fmaf(wb.y, qb.y, dot);
        dot = fmaf(wb.z, qb.z, dot); dot = fmaf(wb.w, qb.w, dot);
        float zo = dot + ldsOb[d];
        outZoQ[(size_t)d * 2048] = zo;
        r[k] -= zo;
      }
    }
  }
  // ---- z_O = z - r_final ----
  #pragma unroll
  for (int k = 0; k < 64; ++k) {
    int d = dg * 64 + k;
    outZO[(size_t)(b * 512 + d) * 2048 + t] = zb[(size_t)d * 2048 + t] - r[k];
  }
}

extern "C" void kernel_launch(void* const* d_in, const int* in_sizes, int n_in,
                              void* d_out, int out_size, void* d_ws, size_t ws_size,
                              hipStream_t stream) {
  const float* z     = (const float*)d_in[0];
  const float* in_v  = (const float*)d_in[1];
  const float* in_g  = (const float*)d_in[2];
  const float* in_b  = (const float*)d_in[3];
  const float* out_v = (const float*)d_in[4];
  const float* out_g = (const float*)d_in[5];
  const float* out_b = (const float*)d_in[6];
  const float* cbs   = (const float*)d_in[7];
  float* out = (float*)d_out;
  float* ws  = (float*)d_ws;

  hipLaunchKernelGGL(rvq_prep, dim3(9), dim3(256), 0, stream,
                     in_v, in_g, out_v, out_g, cbs, ws);
  hipLaunchKernelGGL(rvq_main, dim3(64, 16), dim3(256), 0, stream,
                     z, in_b, out_b, cbs, ws, out);
}